// Round 2
// baseline (426.264 us; speedup 1.0000x reference)
//
#include <hip/hip_runtime.h>
#include <hip/hip_bf16.h>
#include <stdint.h>

// Problem dims (fixed by reference)
#define HH 224
#define WW 224
#define CC 1024
#define BB 256
#define KK (HH*WW)            // 50176
#define EPSILON_F 0.001f
#define LOG2E 1.4426950408889634f
#define INVN (1.0f/50176.0f)
// clip(v,±2000)/N == clip(v/N, ±2000/N) since 1/N > 0
#define CLAMP_V (2000.0f/50176.0f)

// K-split: 112 chunks of 448 = 2 rows of 224. Each 32-wide K-step lies in one image row.
// grid = 8 x 2 x 112 = 1792 blocks = 7 blocks/CU (occupancy was the R1 bottleneck: 2 blocks/CU).
#define KCHUNKS 112
#define ROWS_PER_CHUNK 2
#define STEPS_PER_ROW 7       // 224/32

// 36 elems = 72 B rows: 16-row b128 bank starts (18*r)%32 all distinct -> <=2-way overlap (free)
#define LDS_STRIDE 36

typedef __bf16 bf16x8 __attribute__((ext_vector_type(8)));
typedef float  f32x4  __attribute__((ext_vector_type(4)));

// ---------------- prepass: x fp32 -> bf16 (halves A fetch, kills cvt VALU in main) ---------
__global__ __launch_bounds__(256)
void cvt_bf16_kernel(const float* __restrict__ x, __hip_bfloat16* __restrict__ xb, int n8) {
    int i = blockIdx.x * 256 + threadIdx.x;   // one thread per 8 elements
    if (i >= n8) return;
    const float4* p = (const float4*)(x + (size_t)i * 8);
    float4 a = p[0], b = p[1];
    union { __hip_bfloat16 h[8]; uint4 u; } o;
    o.h[0] = (__hip_bfloat16)a.x; o.h[1] = (__hip_bfloat16)a.y;
    o.h[2] = (__hip_bfloat16)a.z; o.h[3] = (__hip_bfloat16)a.w;
    o.h[4] = (__hip_bfloat16)b.x; o.h[5] = (__hip_bfloat16)b.y;
    o.h[6] = (__hip_bfloat16)b.z; o.h[7] = (__hip_bfloat16)b.w;
    *(uint4*)(xb + (size_t)i * 8) = o.u;
}

// ---------------- main fused curve-gen + GEMM -------------------------------------------
template <bool BF16A>
__global__ __launch_bounds__(256, BF16A ? 7 : 4)
void blob_gemm_kernel(const void* __restrict__ xin,
                      const float* __restrict__ pos,
                      const float* __restrict__ sig,
                      const float* __restrict__ cwt,
                      const float* __restrict__ xs,
                      const float* __restrict__ ys,
                      float* __restrict__ out) {
    __shared__ __bf16 As[128 * LDS_STRIDE];   // A-tile: 128 m-rows x 32 k (bf16)
    __shared__ __bf16 Bs[128 * LDS_STRIDE];   // B^T-tile: 128 c-rows x 32 k (bf16)
    __shared__ float  xrow[WW];               // x_axis (xs row 0), reused every row
    __shared__ float  ycol[ROWS_PER_CHUNK];   // y_axis values for this chunk's rows

    const int tid  = threadIdx.x;
    const int wave = tid >> 6;
    const int lane = tid & 63;

    const int c0 = blockIdx.x * 128;              // N-tile (8)
    const int m0 = blockIdx.y * 128;              // M-tile (2)
    const int k0 = blockIdx.z * (ROWS_PER_CHUNK * WW);  // K-chunk (112)

    // ---- preload axis values ----
    if (tid < WW) xrow[tid] = xs[tid];                       // xs[0*W + w] = x_axis[w]
    if (tid >= WW && tid < WW + ROWS_PER_CHUNK) {
        int r = tid - WW;
        int h = blockIdx.z * ROWS_PER_CHUNK + r;
        ycol[r] = ys[h * WW];                                // ys[h*W + 0] = y_axis[h]
    }

    // ---- per-thread curve params: this thread generates 2 groups of 8 curve elems/step ----
    const int q    = tid & 3;           // k-octet within 32-wide step
    const int cr0  = tid >> 2;          // 0..63: LDS row (c or m)
    float A2[2], S2[2], P1[2], P0[2], EYC[2];
#pragma unroll
    for (int g = 0; g < 2; ++g) {
        int c = c0 + (g << 6) + cr0;
        float s  = sig[c];
        float w  = cwt[c];
        float s2 = s * s;
        A2[g] = w / (6.283185307179586f * s2 + EPSILON_F) * INVN;  // factor*cw/N
        S2[g] = LOG2E / (2.0f * s2 + EPSILON_F);                   // log2e / two_sig2
        P0[g] = pos[2 * c];       // y position
        P1[g] = pos[2 * c + 1];   // x position
    }

    // LDS write pointers
    __bf16* as_w0 = As + cr0 * LDS_STRIDE + q * 8;
    __bf16* as_w1 = As + (64 + cr0) * LDS_STRIDE + q * 8;
    __bf16* bs_w0 = Bs + cr0 * LDS_STRIDE + q * 8;
    __bf16* bs_w1 = Bs + (64 + cr0) * LDS_STRIDE + q * 8;

    // A-stage global bases
    const float* agf0 = (const float*)xin + (size_t)(m0 + cr0) * KK + k0 + q * 8;
    const float* agf1 = (const float*)xin + (size_t)(m0 + 64 + cr0) * KK + k0 + q * 8;
    const __hip_bfloat16* agb0 = (const __hip_bfloat16*)xin + (size_t)(m0 + cr0) * KK + k0 + q * 8;
    const __hip_bfloat16* agb1 = (const __hip_bfloat16*)xin + (size_t)(m0 + 64 + cr0) * KK + k0 + q * 8;

    // wave quadrant: 2x2 waves of 64x64
    const int wm = (wave & 1) * 64;
    const int wn = (wave >> 1) * 64;
    const int fl = lane & 15;
    const int fk = (lane >> 4) * 8;
    const __bf16* ar = As + (wm + fl) * LDS_STRIDE + fk;
    const __bf16* br = Bs + (wn + fl) * LDS_STRIDE + fk;

    f32x4 acc[4][4];
#pragma unroll
    for (int i = 0; i < 4; ++i)
#pragma unroll
        for (int j = 0; j < 4; ++j) acc[i][j] = (f32x4){0.f, 0.f, 0.f, 0.f};

    __syncthreads();  // xrow/ycol ready

#pragma unroll 1
    for (int r = 0; r < ROWS_PER_CHUNK; ++r) {
        const float ysv = ycol[r];
        {
            float dy0 = ysv - P0[0]; EYC[0] = dy0 * dy0 * S2[0];
            float dy1 = ysv - P0[1]; EYC[1] = dy1 * dy1 * S2[1];
        }
#pragma unroll 1
        for (int wb = 0; wb < STEPS_PER_ROW; ++wb) {
            const int kb = r * WW + wb * 32;  // offset within chunk

            // issue A loads early
            union { __bf16 h[8]; uint4 u; } av0, av1;
            if (BF16A) {
                av0.u = *(const uint4*)(agb0 + kb);
                av1.u = *(const uint4*)(agb1 + kb);
            } else {
                float4 a00 = *(const float4*)(agf0 + kb);
                float4 a01 = *(const float4*)(agf0 + kb + 4);
                float4 a10 = *(const float4*)(agf1 + kb);
                float4 a11 = *(const float4*)(agf1 + kb + 4);
                av0.h[0] = (__bf16)a00.x; av0.h[1] = (__bf16)a00.y;
                av0.h[2] = (__bf16)a00.z; av0.h[3] = (__bf16)a00.w;
                av0.h[4] = (__bf16)a01.x; av0.h[5] = (__bf16)a01.y;
                av0.h[6] = (__bf16)a01.z; av0.h[7] = (__bf16)a01.w;
                av1.h[0] = (__bf16)a10.x; av1.h[1] = (__bf16)a10.y;
                av1.h[2] = (__bf16)a10.z; av1.h[3] = (__bf16)a10.w;
                av1.h[4] = (__bf16)a11.x; av1.h[5] = (__bf16)a11.y;
                av1.h[6] = (__bf16)a11.z; av1.h[7] = (__bf16)a11.w;
            }

            // x-axis values for this thread's k-octet (same for both c-groups)
            float4 xv0 = *(const float4*)(xrow + wb * 32 + q * 8);
            float4 xv1 = *(const float4*)(xrow + wb * 32 + q * 8 + 4);
            float xv[8] = {xv0.x, xv0.y, xv0.z, xv0.w, xv1.x, xv1.y, xv1.z, xv1.w};

            // generate 16 curve values -> bf16
            union { __bf16 h[8]; uint4 u; } cv0, cv1;
#pragma unroll
            for (int i = 0; i < 8; ++i) {
                float dx0 = xv[i] - P1[0];
                float t0  = __builtin_fmaf(dx0 * S2[0], dx0, EYC[0]);
                float v0  = __builtin_amdgcn_exp2f(-t0) * A2[0];
                v0 = fminf(fmaxf(v0, -CLAMP_V), CLAMP_V);
                cv0.h[i] = (__bf16)v0;
                float dx1 = xv[i] - P1[1];
                float t1  = __builtin_fmaf(dx1 * S2[1], dx1, EYC[1]);
                float v1  = __builtin_amdgcn_exp2f(-t1) * A2[1];
                v1 = fminf(fmaxf(v1, -CLAMP_V), CLAMP_V);
                cv1.h[i] = (__bf16)v1;
            }

            __syncthreads();  // previous iteration's fragment reads done
            *(uint4*)bs_w0 = cv0.u;
            *(uint4*)bs_w1 = cv1.u;
            *(uint4*)as_w0 = av0.u;
            *(uint4*)as_w1 = av1.u;
            __syncthreads();

            // fragments + 16 MFMAs
            bf16x8 af[4], bf[4];
#pragma unroll
            for (int i = 0; i < 4; ++i) {
                af[i] = *(const bf16x8*)(ar + i * 16 * LDS_STRIDE);
                bf[i] = *(const bf16x8*)(br + i * 16 * LDS_STRIDE);
            }
#pragma unroll
            for (int mi = 0; mi < 4; ++mi)
#pragma unroll
                for (int ni = 0; ni < 4; ++ni)
                    acc[mi][ni] = __builtin_amdgcn_mfma_f32_16x16x32_bf16(
                        af[mi], bf[ni], acc[mi][ni], 0, 0, 0);
        }
    }

    // epilogue: C/D layout col=lane&15, row=(lane>>4)*4+reg  -> atomicAdd (K-split)
    const int orow = (lane >> 4) * 4;
#pragma unroll
    for (int mi = 0; mi < 4; ++mi) {
        int m = m0 + wm + mi * 16 + orow;
#pragma unroll
        for (int ni = 0; ni < 4; ++ni) {
            int c = c0 + wn + ni * 16 + fl;
#pragma unroll
            for (int v = 0; v < 4; ++v)
                atomicAdd(out + (size_t)(m + v) * CC + c, acc[mi][ni][v]);
        }
    }
}

extern "C" void kernel_launch(void* const* d_in, const int* in_sizes, int n_in,
                              void* d_out, int out_size, void* d_ws, size_t ws_size,
                              hipStream_t stream) {
    const float* x   = (const float*)d_in[0];
    const float* pos = (const float*)d_in[1];
    const float* sg  = (const float*)d_in[2];
    const float* cw  = (const float*)d_in[3];
    const float* xs  = (const float*)d_in[4];
    const float* ys  = (const float*)d_in[5];
    float* out = (float*)d_out;

    // K-split partials accumulate via atomicAdd -> zero output first
    hipMemsetAsync(out, 0, (size_t)BB * CC * sizeof(float), stream);

    dim3 grid(CC / 128, BB / 128, KCHUNKS);  // (8, 2, 112) = 1792 blocks = 7/CU

    const size_t nx = (size_t)BB * KK;                  // 12.85M elements
    const size_t need = nx * sizeof(__hip_bfloat16);    // 25.7 MB
    if (ws_size >= need) {
        __hip_bfloat16* xb = (__hip_bfloat16*)d_ws;
        int n8 = (int)(nx / 8);                          // KK%8==0, exact
        cvt_bf16_kernel<<<(n8 + 255) / 256, 256, 0, stream>>>(x, xb, n8);
        blob_gemm_kernel<true><<<grid, 256, 0, stream>>>(xb, pos, sg, cw, xs, ys, out);
    } else {
        blob_gemm_kernel<false><<<grid, 256, 0, stream>>>(x, pos, sg, cw, xs, ys, out);
    }
}

// Round 3
// 261.884 us; speedup vs baseline: 1.6277x; 1.6277x over previous
//
#include <hip/hip_runtime.h>
#include <hip/hip_bf16.h>
#include <stdint.h>

// Problem dims (fixed by reference)
#define HH 224
#define WW 224
#define CC 1024
#define BB 256
#define KK (HH*WW)            // 50176
#define EPSILON_F 0.001f
#define LOG2E 1.4426950408889634f
#define INVN (1.0f/50176.0f)
// clip(v,±2000)/N == clip(v/N, ±2000/N) since 1/N > 0
#define CLAMP_V (2000.0f/50176.0f)

// K-split: 112 chunks of 448 = 2 rows of 224. Each 32-wide K-step lies in one image row.
// grid = 8 x 2 x 112 = 1792 blocks = 7 blocks/CU.
#define KCHUNKS 112
#define ROWS_PER_CHUNK 2
#define STEPS_PER_ROW 7       // 224/32

// 36 elems = 72 B rows: 16-row b128 bank starts (18*r)%32 all distinct -> <=2-way overlap (free)
#define LDS_STRIDE 36

typedef __bf16 bf16x8 __attribute__((ext_vector_type(8)));
typedef float  f32x4  __attribute__((ext_vector_type(4)));

// ---------------- prepass: x fp32 -> bf16 (halves A fetch, kills cvt VALU in main) ---------
__global__ __launch_bounds__(256)
void cvt_bf16_kernel(const float* __restrict__ x, __hip_bfloat16* __restrict__ xb, int n8) {
    int i = blockIdx.x * 256 + threadIdx.x;   // one thread per 8 elements
    if (i >= n8) return;
    const float4* p = (const float4*)(x + (size_t)i * 8);
    float4 a = p[0], b = p[1];
    union { __hip_bfloat16 h[8]; uint4 u; } o;
    o.h[0] = (__hip_bfloat16)a.x; o.h[1] = (__hip_bfloat16)a.y;
    o.h[2] = (__hip_bfloat16)a.z; o.h[3] = (__hip_bfloat16)a.w;
    o.h[4] = (__hip_bfloat16)b.x; o.h[5] = (__hip_bfloat16)b.y;
    o.h[6] = (__hip_bfloat16)b.z; o.h[7] = (__hip_bfloat16)b.w;
    *(uint4*)(xb + (size_t)i * 8) = o.u;
}

// ---------------- main fused curve-gen + GEMM -------------------------------------------
// NOTE: no min-waves arg in __launch_bounds__! R2 set (256,7): compiler capped VGPRs at 36,
// spilled the 64-reg accumulator to scratch -> 1.55 GB spill traffic, 4x slower. The natural
// allocation (~72 VGPR, accs in unified AGPR file) already permits 7 blocks/CU.
template <bool BF16A>
__global__ __launch_bounds__(256)
void blob_gemm_kernel(const void* __restrict__ xin,
                      const float* __restrict__ pos,
                      const float* __restrict__ sig,
                      const float* __restrict__ cwt,
                      const float* __restrict__ xs,
                      const float* __restrict__ ys,
                      float* __restrict__ out) {
    __shared__ __bf16 As[128 * LDS_STRIDE];   // A-tile: 128 m-rows x 32 k (bf16)
    __shared__ __bf16 Bs[128 * LDS_STRIDE];   // B^T-tile: 128 c-rows x 32 k (bf16)
    __shared__ float  xrow[WW];               // x_axis (xs row 0), reused every row
    __shared__ float  ycol[ROWS_PER_CHUNK];   // y_axis values for this chunk's rows

    const int tid  = threadIdx.x;
    const int wave = tid >> 6;
    const int lane = tid & 63;

    const int c0 = blockIdx.x * 128;              // N-tile (8)
    const int m0 = blockIdx.y * 128;              // M-tile (2)
    const int k0 = blockIdx.z * (ROWS_PER_CHUNK * WW);  // K-chunk (112)

    // ---- preload axis values ----
    if (tid < WW) xrow[tid] = xs[tid];                       // xs[0*W + w] = x_axis[w]
    if (tid >= WW && tid < WW + ROWS_PER_CHUNK) {
        int r = tid - WW;
        int h = blockIdx.z * ROWS_PER_CHUNK + r;
        ycol[r] = ys[h * WW];                                // ys[h*W + 0] = y_axis[h]
    }

    // ---- per-thread curve params: this thread generates 2 groups of 8 curve elems/step ----
    const int q    = tid & 3;           // k-octet within 32-wide step
    const int cr0  = tid >> 2;          // 0..63: LDS row (c or m)
    float A2[2], S2[2], P1[2], P0[2], EYC[2];
#pragma unroll
    for (int g = 0; g < 2; ++g) {
        int c = c0 + (g << 6) + cr0;
        float s  = sig[c];
        float w  = cwt[c];
        float s2 = s * s;
        A2[g] = w / (6.283185307179586f * s2 + EPSILON_F) * INVN;  // factor*cw/N
        S2[g] = LOG2E / (2.0f * s2 + EPSILON_F);                   // log2e / two_sig2
        P0[g] = pos[2 * c];       // y position
        P1[g] = pos[2 * c + 1];   // x position
    }

    // LDS write pointers
    __bf16* as_w0 = As + cr0 * LDS_STRIDE + q * 8;
    __bf16* as_w1 = As + (64 + cr0) * LDS_STRIDE + q * 8;
    __bf16* bs_w0 = Bs + cr0 * LDS_STRIDE + q * 8;
    __bf16* bs_w1 = Bs + (64 + cr0) * LDS_STRIDE + q * 8;

    // A-stage global bases
    const float* agf0 = (const float*)xin + (size_t)(m0 + cr0) * KK + k0 + q * 8;
    const float* agf1 = (const float*)xin + (size_t)(m0 + 64 + cr0) * KK + k0 + q * 8;
    const __hip_bfloat16* agb0 = (const __hip_bfloat16*)xin + (size_t)(m0 + cr0) * KK + k0 + q * 8;
    const __hip_bfloat16* agb1 = (const __hip_bfloat16*)xin + (size_t)(m0 + 64 + cr0) * KK + k0 + q * 8;

    // wave quadrant: 2x2 waves of 64x64
    const int wm = (wave & 1) * 64;
    const int wn = (wave >> 1) * 64;
    const int fl = lane & 15;
    const int fk = (lane >> 4) * 8;
    const __bf16* ar = As + (wm + fl) * LDS_STRIDE + fk;
    const __bf16* br = Bs + (wn + fl) * LDS_STRIDE + fk;

    f32x4 acc[4][4];
#pragma unroll
    for (int i = 0; i < 4; ++i)
#pragma unroll
        for (int j = 0; j < 4; ++j) acc[i][j] = (f32x4){0.f, 0.f, 0.f, 0.f};

    __syncthreads();  // xrow/ycol ready

#pragma unroll 1
    for (int r = 0; r < ROWS_PER_CHUNK; ++r) {
        const float ysv = ycol[r];
        {
            float dy0 = ysv - P0[0]; EYC[0] = dy0 * dy0 * S2[0];
            float dy1 = ysv - P0[1]; EYC[1] = dy1 * dy1 * S2[1];
        }
#pragma unroll 1
        for (int wb = 0; wb < STEPS_PER_ROW; ++wb) {
            const int kb = r * WW + wb * 32;  // offset within chunk

            // issue A loads early
            union { __bf16 h[8]; uint4 u; } av0, av1;
            if (BF16A) {
                av0.u = *(const uint4*)(agb0 + kb);
                av1.u = *(const uint4*)(agb1 + kb);
            } else {
                float4 a00 = *(const float4*)(agf0 + kb);
                float4 a01 = *(const float4*)(agf0 + kb + 4);
                float4 a10 = *(const float4*)(agf1 + kb);
                float4 a11 = *(const float4*)(agf1 + kb + 4);
                av0.h[0] = (__bf16)a00.x; av0.h[1] = (__bf16)a00.y;
                av0.h[2] = (__bf16)a00.z; av0.h[3] = (__bf16)a00.w;
                av0.h[4] = (__bf16)a01.x; av0.h[5] = (__bf16)a01.y;
                av0.h[6] = (__bf16)a01.z; av0.h[7] = (__bf16)a01.w;
                av1.h[0] = (__bf16)a10.x; av1.h[1] = (__bf16)a10.y;
                av1.h[2] = (__bf16)a10.z; av1.h[3] = (__bf16)a10.w;
                av1.h[4] = (__bf16)a11.x; av1.h[5] = (__bf16)a11.y;
                av1.h[6] = (__bf16)a11.z; av1.h[7] = (__bf16)a11.w;
            }

            // x-axis values for this thread's k-octet (same for both c-groups)
            float4 xv0 = *(const float4*)(xrow + wb * 32 + q * 8);
            float4 xv1 = *(const float4*)(xrow + wb * 32 + q * 8 + 4);
            float xv[8] = {xv0.x, xv0.y, xv0.z, xv0.w, xv1.x, xv1.y, xv1.z, xv1.w};

            // generate 16 curve values -> bf16
            union { __bf16 h[8]; uint4 u; } cv0, cv1;
#pragma unroll
            for (int i = 0; i < 8; ++i) {
                float dx0 = xv[i] - P1[0];
                float t0  = __builtin_fmaf(dx0 * S2[0], dx0, EYC[0]);
                float v0  = __builtin_amdgcn_exp2f(-t0) * A2[0];
                v0 = fminf(fmaxf(v0, -CLAMP_V), CLAMP_V);
                cv0.h[i] = (__bf16)v0;
                float dx1 = xv[i] - P1[1];
                float t1  = __builtin_fmaf(dx1 * S2[1], dx1, EYC[1]);
                float v1  = __builtin_amdgcn_exp2f(-t1) * A2[1];
                v1 = fminf(fmaxf(v1, -CLAMP_V), CLAMP_V);
                cv1.h[i] = (__bf16)v1;
            }

            __syncthreads();  // previous iteration's fragment reads done
            *(uint4*)bs_w0 = cv0.u;
            *(uint4*)bs_w1 = cv1.u;
            *(uint4*)as_w0 = av0.u;
            *(uint4*)as_w1 = av1.u;
            __syncthreads();

            // fragments + 16 MFMAs
            bf16x8 af[4], bf[4];
#pragma unroll
            for (int i = 0; i < 4; ++i) {
                af[i] = *(const bf16x8*)(ar + i * 16 * LDS_STRIDE);
                bf[i] = *(const bf16x8*)(br + i * 16 * LDS_STRIDE);
            }
#pragma unroll
            for (int mi = 0; mi < 4; ++mi)
#pragma unroll
                for (int ni = 0; ni < 4; ++ni)
                    acc[mi][ni] = __builtin_amdgcn_mfma_f32_16x16x32_bf16(
                        af[mi], bf[ni], acc[mi][ni], 0, 0, 0);
        }
    }

    // epilogue: C/D layout col=lane&15, row=(lane>>4)*4+reg  -> atomicAdd (K-split)
    const int orow = (lane >> 4) * 4;
#pragma unroll
    for (int mi = 0; mi < 4; ++mi) {
        int m = m0 + wm + mi * 16 + orow;
#pragma unroll
        for (int ni = 0; ni < 4; ++ni) {
            int c = c0 + wn + ni * 16 + fl;
#pragma unroll
            for (int v = 0; v < 4; ++v)
                atomicAdd(out + (size_t)(m + v) * CC + c, acc[mi][ni][v]);
        }
    }
}

extern "C" void kernel_launch(void* const* d_in, const int* in_sizes, int n_in,
                              void* d_out, int out_size, void* d_ws, size_t ws_size,
                              hipStream_t stream) {
    const float* x   = (const float*)d_in[0];
    const float* pos = (const float*)d_in[1];
    const float* sg  = (const float*)d_in[2];
    const float* cw  = (const float*)d_in[3];
    const float* xs  = (const float*)d_in[4];
    const float* ys  = (const float*)d_in[5];
    float* out = (float*)d_out;

    // K-split partials accumulate via atomicAdd -> zero output first
    hipMemsetAsync(out, 0, (size_t)BB * CC * sizeof(float), stream);

    dim3 grid(CC / 128, BB / 128, KCHUNKS);  // (8, 2, 112) = 1792 blocks = 7/CU

    const size_t nx = (size_t)BB * KK;                  // 12.85M elements
    const size_t need = nx * sizeof(__hip_bfloat16);    // 25.7 MB
    if (ws_size >= need) {
        __hip_bfloat16* xb = (__hip_bfloat16*)d_ws;
        int n8 = (int)(nx / 8);                          // KK%8==0, exact
        cvt_bf16_kernel<<<(n8 + 255) / 256, 256, 0, stream>>>(x, xb, n8);
        blob_gemm_kernel<true><<<grid, 256, 0, stream>>>(xb, pos, sg, cw, xs, ys, out);
    } else {
        blob_gemm_kernel<false><<<grid, 256, 0, stream>>>(x, pos, sg, cw, xs, ys, out);
    }
}

// Round 4
// 158.261 us; speedup vs baseline: 2.6934x; 1.6548x over previous
//
#include <hip/hip_runtime.h>
#include <hip/hip_bf16.h>
#include <stdint.h>

// Problem dims (fixed by reference)
#define HH 224
#define WW 224
#define CC 1024
#define BB 256
#define KK (HH*WW)            // 50176
#define EPSILON_F 0.001f
#define LOG2E 1.4426950408889634f
#define INVN (1.0f/50176.0f)
// clip(v,+-2000)/N == clip(v/N, +-2000/N) since 1/N > 0
#define CLAMP_V (2000.0f/50176.0f)

// K-split: 32 chunks of 7 rows. Tile: 256m x 64c, 4 waves (each 64x64).
// grid = 16 c-tiles x 32 k-chunks = 512 blocks = 2 blocks/CU.
// B-curves generated once per (c,k) (M-dim not split). Partials -> ws, reduced after
// (R3 lesson: 29.4M atomicAdds serialized the chip; plain stores + reduce instead).
#define KCHUNKS 32
#define ROWS_PER_CHUNK 7
#define STEPS 49              // 7 wb * 7 rows

// 36 elems = 72 B rows: 16-row b128 bank starts (18*r)%32 all distinct -> <=2-way (free)
#define LDS_STRIDE 36

typedef __bf16 bf16x8 __attribute__((ext_vector_type(8)));
typedef float  f32x4  __attribute__((ext_vector_type(4)));

// ---------------- prepass: x fp32 -> bf16 -------------------------------------------------
__global__ __launch_bounds__(256)
void cvt_bf16_kernel(const float* __restrict__ x, __hip_bfloat16* __restrict__ xb, int n8) {
    int i = blockIdx.x * 256 + threadIdx.x;   // one thread per 8 elements
    if (i >= n8) return;
    const float4* p = (const float4*)(x + (size_t)i * 8);
    float4 a = p[0], b = p[1];
    union { __hip_bfloat16 h[8]; uint4 u; } o;
    o.h[0] = (__hip_bfloat16)a.x; o.h[1] = (__hip_bfloat16)a.y;
    o.h[2] = (__hip_bfloat16)a.z; o.h[3] = (__hip_bfloat16)a.w;
    o.h[4] = (__hip_bfloat16)b.x; o.h[5] = (__hip_bfloat16)b.y;
    o.h[6] = (__hip_bfloat16)b.z; o.h[7] = (__hip_bfloat16)b.w;
    *(uint4*)(xb + (size_t)i * 8) = o.u;
}

// ---------------- reduce: out[m][c] = sum_z part[z][m][c] --------------------------------
__global__ __launch_bounds__(256)
void reduce_kernel(const float* __restrict__ part, float* __restrict__ out) {
    int i = blockIdx.x * 256 + threadIdx.x;          // 65536 float4 slots
    const f32x4* p = (const f32x4*)part + i;
    f32x4 s = {0.f, 0.f, 0.f, 0.f};
#pragma unroll
    for (int z = 0; z < KCHUNKS; ++z)
        s += p[(size_t)z * (BB * CC / 4)];
    ((f32x4*)out)[i] = s;
}

// ---------------- main fused curve-gen + GEMM --------------------------------------------
// NOTE: no min-waves arg in __launch_bounds__ (R2: (256,7) spilled the accumulator).
template <bool BF16A, bool PARTIAL>
__global__ __launch_bounds__(256)
void blob_gemm_kernel(const void* __restrict__ xin,
                      const float* __restrict__ pos,
                      const float* __restrict__ sig,
                      const float* __restrict__ cwt,
                      const float* __restrict__ xs,
                      const float* __restrict__ ys,
                      float* __restrict__ dst) {
    // double-buffered tiles
    __shared__ __bf16 As[2][256 * LDS_STRIDE];   // 256 m-rows x 32 k
    __shared__ __bf16 Bs[2][64 * LDS_STRIDE];    // 64 c-rows x 32 k
    __shared__ float  xrow[WW];
    __shared__ float  ycol[ROWS_PER_CHUNK];

    const int tid  = threadIdx.x;
    const int wave = tid >> 6;
    const int lane = tid & 63;

    const int c0 = blockIdx.x * 64;                    // N-tile (16)
    const int z  = blockIdx.y;                         // K-chunk (32)
    const int k0 = z * (ROWS_PER_CHUNK * WW);

    if (tid < WW) xrow[tid] = xs[tid];                 // x_axis
    if (tid >= WW && tid < WW + ROWS_PER_CHUNK)
        ycol[tid - WW] = ys[(z * ROWS_PER_CHUNK + (tid - WW)) * WW];  // y_axis

    // ---- per-thread curve params: one c per thread, one k-octet ----
    const int q   = tid & 3;            // k-octet within 32-wide step
    const int cr0 = tid >> 2;           // 0..63: c-row
    const int c   = c0 + cr0;
    float A2, S2, P0, P1;
    {
        float s  = sig[c];
        float w  = cwt[c];
        float s2 = s * s;
        A2 = w / (6.283185307179586f * s2 + EPSILON_F) * INVN;
        S2 = LOG2E / (2.0f * s2 + EPSILON_F);
        P0 = pos[2 * c];
        P1 = pos[2 * c + 1];
    }

    // A staging: 4 rows per thread (cr0 + 64j), octet q
    const __hip_bfloat16* agb[4];
    const float* agf[4];
#pragma unroll
    for (int j = 0; j < 4; ++j) {
        size_t off = (size_t)(cr0 + 64 * j) * KK + k0 + q * 8;
        agb[j] = (const __hip_bfloat16*)xin + off;
        agf[j] = (const float*)xin + off;
    }
    const int as_w = cr0 * LDS_STRIDE + q * 8;         // + 64j*LDS_STRIDE per row
    const int bs_w = cr0 * LDS_STRIDE + q * 8;

    // wave m-quadrant: wave w covers m rows [64w, 64w+64), all 64 c
    const int wm = wave * 64;
    const int fl = lane & 15;
    const int fk = (lane >> 4) * 8;
    const int ar_off = (wm + fl) * LDS_STRIDE + fk;
    const int br_off = fl * LDS_STRIDE + fk;

    f32x4 acc[4][4];
#pragma unroll
    for (int i = 0; i < 4; ++i)
#pragma unroll
        for (int j = 0; j < 4; ++j) acc[i][j] = (f32x4){0.f, 0.f, 0.f, 0.f};

    __syncthreads();   // axes ready

    // y-axis values into registers (7 broadcast LDS reads, once)
    float ycolr[ROWS_PER_CHUNK];
#pragma unroll
    for (int r = 0; r < ROWS_PER_CHUNK; ++r) ycolr[r] = ycol[r];

    // ---- Ex for wb=0 + stage step 0 into buffer 0 ----
    float Ex[8];
    {
        float4 xv0 = *(const float4*)(xrow + q * 8);
        float4 xv1 = *(const float4*)(xrow + q * 8 + 4);
        float xv[8] = {xv0.x, xv0.y, xv0.z, xv0.w, xv1.x, xv1.y, xv1.z, xv1.w};
#pragma unroll
        for (int i = 0; i < 8; ++i) {
            float dx = xv[i] - P1;
            Ex[i] = __builtin_amdgcn_exp2f(-(dx * S2 * dx));
        }
        float dy  = ycolr[0] - P0;
        float eyA = __builtin_amdgcn_exp2f(-(dy * S2 * dy)) * A2;
        union { __bf16 h[8]; uint4 u; } cv;
#pragma unroll
        for (int i = 0; i < 8; ++i) {
            float v = Ex[i] * eyA;
            cv.h[i] = (__bf16)fminf(fmaxf(v, -CLAMP_V), CLAMP_V);
        }
        *(uint4*)(&Bs[0][bs_w]) = cv.u;
#pragma unroll
        for (int j = 0; j < 4; ++j) {
            union { __bf16 h[8]; uint4 u; } av;
            if (BF16A) {
                av.u = *(const uint4*)(agb[j]);
            } else {
                float4 f0 = *(const float4*)(agf[j]);
                float4 f1 = *(const float4*)(agf[j] + 4);
                av.h[0] = (__bf16)f0.x; av.h[1] = (__bf16)f0.y;
                av.h[2] = (__bf16)f0.z; av.h[3] = (__bf16)f0.w;
                av.h[4] = (__bf16)f1.x; av.h[5] = (__bf16)f1.y;
                av.h[6] = (__bf16)f1.z; av.h[7] = (__bf16)f1.w;
            }
            *(uint4*)(&As[0][as_w + 64 * j * LDS_STRIDE]) = av.u;
        }
    }
    __syncthreads();   // buffer 0 ready

    // ---- main loop: step s computes on buf(s&1); stages s+1 into buf(s&1)^1; 1 barrier ----
    int nr = 1, nwb = 0;   // (row, wb) of the step being staged (s+1)
#pragma unroll 2
    for (int s = 0; s < STEPS; ++s) {
        const int cb = s & 1;

        // 1. prefetch next A into registers (longest latency first)
        uint4  pa[4];
        float4 pf0[4], pf1[4];
        if (s < STEPS - 1) {
            const int koff = nr * WW + nwb * 32;   // wave-uniform
            if (BF16A) {
#pragma unroll
                for (int j = 0; j < 4; ++j) pa[j] = *(const uint4*)(agb[j] + koff);
            } else {
#pragma unroll
                for (int j = 0; j < 4; ++j) {
                    pf0[j] = *(const float4*)(agf[j] + koff);
                    pf1[j] = *(const float4*)(agf[j] + koff + 4);
                }
            }
        }

        // 2. fragments + 16 MFMAs on current buffer
        bf16x8 fa[4], fb[4];
#pragma unroll
        for (int i = 0; i < 4; ++i) {
            fa[i] = *(const bf16x8*)(&As[cb][ar_off + i * 16 * LDS_STRIDE]);
            fb[i] = *(const bf16x8*)(&Bs[cb][br_off + i * 16 * LDS_STRIDE]);
        }
#pragma unroll
        for (int mi = 0; mi < 4; ++mi)
#pragma unroll
            for (int ni = 0; ni < 4; ++ni)
                acc[mi][ni] = __builtin_amdgcn_mfma_f32_16x16x32_bf16(
                    fa[mi], fb[ni], acc[mi][ni], 0, 0, 0);

        // 3. stage step s+1 into the other buffer
        if (s < STEPS - 1) {
            if (nr == 0) {   // new wb: refresh Ex (wave-uniform branch)
                float4 xv0 = *(const float4*)(xrow + nwb * 32 + q * 8);
                float4 xv1 = *(const float4*)(xrow + nwb * 32 + q * 8 + 4);
                float xv[8] = {xv0.x, xv0.y, xv0.z, xv0.w, xv1.x, xv1.y, xv1.z, xv1.w};
#pragma unroll
                for (int i = 0; i < 8; ++i) {
                    float dx = xv[i] - P1;
                    Ex[i] = __builtin_amdgcn_exp2f(-(dx * S2 * dx));
                }
            }
            float dy  = ycolr[nr] - P0;
            float eyA = __builtin_amdgcn_exp2f(-(dy * S2 * dy)) * A2;
            union { __bf16 h[8]; uint4 u; } cv;
#pragma unroll
            for (int i = 0; i < 8; ++i) {
                float v = Ex[i] * eyA;
                cv.h[i] = (__bf16)fminf(fmaxf(v, -CLAMP_V), CLAMP_V);
            }
            *(uint4*)(&Bs[cb ^ 1][bs_w]) = cv.u;
#pragma unroll
            for (int j = 0; j < 4; ++j) {
                union { __bf16 h[8]; uint4 u; } av;
                if (BF16A) {
                    av.u = pa[j];
                } else {
                    av.h[0] = (__bf16)pf0[j].x; av.h[1] = (__bf16)pf0[j].y;
                    av.h[2] = (__bf16)pf0[j].z; av.h[3] = (__bf16)pf0[j].w;
                    av.h[4] = (__bf16)pf1[j].x; av.h[5] = (__bf16)pf1[j].y;
                    av.h[6] = (__bf16)pf1[j].z; av.h[7] = (__bf16)pf1[j].w;
                }
                *(uint4*)(&As[cb ^ 1][as_w + 64 * j * LDS_STRIDE]) = av.u;
            }
            ++nr;
            if (nr == ROWS_PER_CHUNK) { nr = 0; ++nwb; }
        }
        __syncthreads();
    }

    // ---- epilogue: C/D layout col=lane&15, row=(lane>>4)*4+reg ----
    const int orow = (lane >> 4) * 4;
    float* base = PARTIAL ? (dst + (size_t)z * BB * CC) : dst;
#pragma unroll
    for (int mi = 0; mi < 4; ++mi) {
        int m = wm + mi * 16 + orow;
#pragma unroll
        for (int ni = 0; ni < 4; ++ni) {
            int cc = c0 + ni * 16 + fl;
#pragma unroll
            for (int v = 0; v < 4; ++v) {
                if (PARTIAL)
                    base[(size_t)(m + v) * CC + cc] = acc[mi][ni][v];
                else
                    atomicAdd(base + (size_t)(m + v) * CC + cc, acc[mi][ni][v]);
            }
        }
    }
}

extern "C" void kernel_launch(void* const* d_in, const int* in_sizes, int n_in,
                              void* d_out, int out_size, void* d_ws, size_t ws_size,
                              hipStream_t stream) {
    const float* x   = (const float*)d_in[0];
    const float* pos = (const float*)d_in[1];
    const float* sg  = (const float*)d_in[2];
    const float* cw  = (const float*)d_in[3];
    const float* xs  = (const float*)d_in[4];
    const float* ys  = (const float*)d_in[5];
    float* out = (float*)d_out;

    dim3 grid(CC / 64, KCHUNKS);   // (16, 32) = 512 blocks, 2/CU
    const size_t nx   = (size_t)BB * KK;
    const size_t XB   = nx * sizeof(__hip_bfloat16);            // 25.7 MB
    const size_t PART = (size_t)KCHUNKS * BB * CC * 4;          // 33.6 MB
    const int n8 = (int)(nx / 8);

    if (ws_size >= XB + PART) {
        __hip_bfloat16* xb = (__hip_bfloat16*)d_ws;
        float* part = (float*)((char*)d_ws + XB);
        cvt_bf16_kernel<<<(n8 + 255) / 256, 256, 0, stream>>>(x, xb, n8);
        blob_gemm_kernel<true, true><<<grid, 256, 0, stream>>>(xb, pos, sg, cw, xs, ys, part);
        reduce_kernel<<<BB * CC / 4 / 256, 256, 0, stream>>>(part, out);
    } else if (ws_size >= PART) {
        float* part = (float*)d_ws;
        blob_gemm_kernel<false, true><<<grid, 256, 0, stream>>>(x, pos, sg, cw, xs, ys, part);
        reduce_kernel<<<BB * CC / 4 / 256, 256, 0, stream>>>(part, out);
    } else if (ws_size >= XB) {
        __hip_bfloat16* xb = (__hip_bfloat16*)d_ws;
        hipMemsetAsync(out, 0, (size_t)BB * CC * sizeof(float), stream);
        cvt_bf16_kernel<<<(n8 + 255) / 256, 256, 0, stream>>>(x, xb, n8);
        blob_gemm_kernel<true, false><<<grid, 256, 0, stream>>>(xb, pos, sg, cw, xs, ys, out);
    } else {
        hipMemsetAsync(out, 0, (size_t)BB * CC * sizeof(float), stream);
        blob_gemm_kernel<false, false><<<grid, 256, 0, stream>>>(x, pos, sg, cw, xs, ys, out);
    }
}